// Round 6
// baseline (921.252 us; speedup 1.0000x reference)
//
#include <hip/hip_runtime.h>
#include <hip/hip_bf16.h>

// VectorQuantizer forward, MI355X.
// z: [32,128,32,32] fp32, codebook: [2048,128] fp32.
// Outputs (flat fp32, concatenated):
//   loss(1), zq_ste(4194304), perplexity(1), onehot_img(67108864),
//   idx_img(32768), index_hist(65536), softmax_hist(65536),
//   commitment(1), quantization(1), softmax_loss(1)  => 71467013 total.
//
// R6 = R5 resubmitted unchanged (broker timeout; code-split fix never measured).
// R5: code-dim split across wave pairs -> acc[4][16] = 64 VGPRs (R4 showed
// acc[4][32]=128 forced AGPR/scratch split: VGPR_Count=124 < 128 needed,
// VALU-busy 2.3x FMA floor, occupancy 23.8%).

#define K_NUM 2048
#define D_NUM 128
#define B_NUM 32
#define HW_NUM 1024
#define N_NUM 32768

// out offsets (in floats)
#define O_LOSS   0ull
#define O_ZQ     1ull
#define O_PERP   4194305ull
#define O_ONEHOT 4194306ull
#define O_IDX    71303170ull
#define O_IHIST  71335938ull
#define O_SHIST  71401474ull
#define O_COMMIT 71467010ull
#define O_QUANT  71467011ull
#define O_SM     71467012ull

// ws offsets (bytes)
#define WS_IDX    0ull        // 32768 * 4 (int idx per position)
#define WS_SCAL   131072ull   // 2 floats: sum(min_dist), sum(log l)
#define WS_ET     131328ull   // 32*2048*4 floats = 1 MiB, layout [dc][k][4] = -2*e
#define WS_CNORM  1179904ull  // 2048 * 4  (||e_k||^2)
#define WS_HIST   1188096ull  // 2048*2048*4 = 16 MiB per-block softmax-hist partials
#define WS_END    17965312ull

// ---------------------------------------------------------------------------
// K1: eTi[dc][k][0..3] = -2*codebook[k][dc*4..dc*4+3]; cnorm[k] = ||e_k||^2.
// grid 32 x 256.
__global__ void vq_prep(const float* __restrict__ cb, float* __restrict__ eTi,
                        float* __restrict__ cnorm) {
    int k = blockIdx.x * 64 + (threadIdx.x >> 2);
    int q = threadIdx.x & 3;  // dim quarter
    float s = 0.f;
#pragma unroll
    for (int i = 0; i < 8; ++i) {
        int d = q * 32 + i * 4;
        int dc = d >> 2;
        float4 v = *reinterpret_cast<const float4*>(cb + (size_t)k * D_NUM + d);
        s += v.x * v.x + v.y * v.y + v.z * v.z + v.w * v.w;
        float4 w = {-2.f * v.x, -2.f * v.y, -2.f * v.z, -2.f * v.w};
        *reinterpret_cast<float4*>(eTi + ((size_t)dc * K_NUM + k) * 4) = w;
    }
    s += __shfl_xor(s, 1, 64);
    s += __shfl_xor(s, 2, 64);
    if (q == 0) cnorm[k] = s;
}

// ---------------------------------------------------------------------------
// K2: fused distances + argmin + softmax stats + hists. grid 2048 x 512.
// Block owns 16 positions. Wave pair (2*pid, 2*pid+1) shares positions
// pid*4..pid*4+3; even wave handles codes [0,1024), odd wave [1024,2048).
// Lane owns codes k = half*1024 + lane + 64*j, j=0..15 -> acc[4][16] (64 VGPR).
// dist = ||z||^2 + ||e||^2 + dot(z, -2e); the -2 is folded into eTi.
// Rule #20: acc fully unrolled, every access compile-time-indexed.
template <bool WSH>
__global__ __launch_bounds__(512, 2) void vq_main(
    const float* __restrict__ z, const float* __restrict__ eTi,
    const float* __restrict__ cnorm, float* __restrict__ out,
    int* __restrict__ idx_ws, float* __restrict__ scal,
    float* __restrict__ wsh) {
    __shared__ __align__(16) float zt[16][D_NUM];  // 8 KB [pos][d]
    __shared__ __align__(16) float et[8192];       // 32 KB: chunk dc, [k][4]
    __shared__ float hist[K_NUM];                  // 8 KB block softmax hist
    __shared__ float cn[K_NUM];                    // 8 KB ||e||^2
    __shared__ float mm[8][4], ll[8][4];           // per-wave m / l partials
    __shared__ int ib[8][4];                       // per-wave argmin
    __shared__ float ssum[4], slog[4];

    const int tid = threadIdx.x;
    const int lane = tid & 63;
    const int wv = tid >> 6;
    const int pid = wv >> 1;   // wave-pair id: positions pid*4..pid*4+3
    const int half = wv & 1;   // code half
    const int b = blockIdx.x >> 6;        // 64 blocks per batch element
    const int hw0 = (blockIdx.x & 63) * 16;
    const int n0 = blockIdx.x * 16;
    const int k0 = half * 1024 + lane;    // this lane's base code

    for (int i = tid; i < K_NUM; i += 512) {
        hist[i] = 0.f;
        cn[i] = cnorm[i];
    }

    // stage z tile: z[b][d][hw0+pos] -> zt[pos][d]; one float4 per thread
    {
        const float* zb = z + (size_t)b * (D_NUM * HW_NUM) + hw0;
        int d = tid >> 2, q = tid & 3;
        float4 v = *reinterpret_cast<const float4*>(zb + d * HW_NUM + q * 4);
        zt[q * 4 + 0][d] = v.x;
        zt[q * 4 + 1][d] = v.y;
        zt[q * 4 + 2][d] = v.z;
        zt[q * 4 + 3][d] = v.w;
    }
    __syncthreads();

    // ||z||^2 for this pair's 4 positions (butterfly over 64 lanes)
    float znorm[4];
#pragma unroll
    for (int p = 0; p < 4; ++p) {
        int pg = pid * 4 + p;
        float a = zt[pg][lane];
        float c2 = zt[pg][lane + 64];
        float s = a * a + c2 * c2;
        for (int off = 32; off; off >>= 1) s += __shfl_xor(s, off, 64);
        znorm[p] = s;
    }

    float acc[4][16];
#pragma unroll
    for (int p = 0; p < 4; ++p)
#pragma unroll
        for (int j = 0; j < 16; ++j) acc[p][j] = 0.f;

    const float4* e4 = reinterpret_cast<const float4*>(et);
    // main matmul: 32 chunks of 4 dims; one ds_read_b128 per code per chunk
    for (int dc = 0; dc < 32; ++dc) {
        const float4* src = reinterpret_cast<const float4*>(eTi) + dc * 2048;
#pragma unroll
        for (int it = 0; it < 4; ++it)
            reinterpret_cast<float4*>(et)[it * 512 + tid] = src[it * 512 + tid];
        __syncthreads();
        float4 z4[4];
#pragma unroll
        for (int p = 0; p < 4; ++p)
            z4[p] = *reinterpret_cast<const float4*>(&zt[pid * 4 + p][dc * 4]);
#pragma unroll
        for (int j = 0; j < 16; ++j) {
            float4 e = e4[k0 + 64 * j];
#pragma unroll
            for (int p = 0; p < 4; ++p) {
                acc[p][j] = fmaf(z4[p].x, e.x, acc[p][j]);
                acc[p][j] = fmaf(z4[p].y, e.y, acc[p][j]);
                acc[p][j] = fmaf(z4[p].z, e.z, acc[p][j]);
                acc[p][j] = fmaf(z4[p].w, e.w, acc[p][j]);
            }
        }
        __syncthreads();
    }

    // dist = znorm + cnorm + dot'
#pragma unroll
    for (int j = 0; j < 16; ++j) {
        float c = cn[k0 + 64 * j];
#pragma unroll
        for (int p = 0; p < 4; ++p) acc[p][j] += znorm[p] + c;
    }

    // per-wave min/argmin over its half; merge across the pair via LDS
    float mfin[4];
    int ifin[4];
#pragma unroll
    for (int p = 0; p < 4; ++p) {
        float mv = acc[p][0];
        int mi = k0;
#pragma unroll
        for (int j = 1; j < 16; ++j) {
            int kk = k0 + 64 * j;
            if (acc[p][j] < mv) { mv = acc[p][j]; mi = kk; }
        }
        for (int off = 32; off; off >>= 1) {
            float ov = __shfl_xor(mv, off, 64);
            int oi = __shfl_xor(mi, off, 64);
            if (ov < mv || (ov == mv && oi < mi)) { mv = ov; mi = oi; }
        }
        if (lane == 0) { mm[wv][p] = mv; ib[wv][p] = mi; }
        mfin[p] = mv;
        ifin[p] = mi;
    }
    __syncthreads();
#pragma unroll
    for (int p = 0; p < 4; ++p) {
        float mo = mm[wv ^ 1][p];
        int io = ib[wv ^ 1][p];
        if (mo < mfin[p] || (mo == mfin[p] && io < ifin[p])) {
            mfin[p] = mo;
            ifin[p] = io;
        }
    }

    // P = exp(mfin - d) in place (single exp pass); partial l per half
    float lfin[4];
#pragma unroll
    for (int p = 0; p < 4; ++p) {
        float s = 0.f;
#pragma unroll
        for (int j = 0; j < 16; ++j) {
            float t = __expf(mfin[p] - acc[p][j]);
            acc[p][j] = t;
            s += t;
        }
        for (int off = 32; off; off >>= 1) s += __shfl_xor(s, off, 64);
        if (lane == 0) ll[wv][p] = s;
        lfin[p] = s;
    }
    __syncthreads();
    float rinv[4];
#pragma unroll
    for (int p = 0; p < 4; ++p) {
        lfin[p] += ll[wv ^ 1][p];  // both partials use the merged max
        rinv[p] = 1.f / lfin[p];
    }

    // block softmax hist: LDS atomics (4 waves per half, distinct banks per j)
#pragma unroll
    for (int j = 0; j < 16; ++j) {
        float h = 0.f;
#pragma unroll
        for (int p = 0; p < 4; ++p) h += acc[p][j] * rinv[p];
        atomicAdd(&hist[k0 + 64 * j], h);
    }

    if (half == 0 && lane == 0) {
        float summ = 0.f, suml = 0.f;
#pragma unroll
        for (int p = 0; p < 4; ++p) {
            int n = n0 + pid * 4 + p;
            idx_ws[n] = ifin[p];
            out[O_IDX + n] = (float)ifin[p];
            atomicAdd(&out[O_IHIST + (size_t)b * K_NUM + ifin[p]], 1.0f);
            summ += mfin[p];
            suml += __logf(lfin[p]);
        }
        ssum[pid] = summ;
        slog[pid] = suml;
    }
    __syncthreads();
    if (tid == 0) {
        float a = 0.f, g = 0.f;
#pragma unroll
        for (int q = 0; q < 4; ++q) { a += ssum[q]; g += slog[q]; }
        atomicAdd(&scal[0], a);
        atomicAdd(&scal[1], g);
    }
    if (WSH) {
        for (int i = tid; i < K_NUM; i += 512)
            wsh[(size_t)blockIdx.x * K_NUM + i] = hist[i];
    } else {
        for (int i = tid; i < K_NUM; i += 512)
            atomicAdd(&out[O_SHIST + (size_t)b * K_NUM + i], hist[i]);
    }
}

// ---------------------------------------------------------------------------
// K3: softmax_hist reduce: out[b][k] = sum over 64 sub-blocks. grid 256 x 256.
__global__ void vq_hist(const float* __restrict__ wsh, float* __restrict__ out) {
    int gid = blockIdx.x * 256 + threadIdx.x;  // 0..65535 = b*2048 + k
    int b = gid >> 11;
    int k = gid & 2047;
    const float* p = wsh + ((size_t)b * 64) * K_NUM + k;
    float s = 0.f;
#pragma unroll
    for (int sb = 0; sb < 64; ++sb) s += p[(size_t)sb * K_NUM];
    out[O_SHIST + gid] = s;
}

// ---------------------------------------------------------------------------
// K4: scatter ones into memset-zeroed onehot_img. grid 128 x 256.
__global__ void vq_scatter(const int* __restrict__ idx, float* __restrict__ out) {
    int n = blockIdx.x * 256 + threadIdx.x;  // 0..32767
    int b = n >> 10;
    int hw = n & 1023;
    int k = idx[n];
    out[O_ONEHOT + (((size_t)b * K_NUM + k) << 10) + hw] = 1.0f;
}

// ---------------------------------------------------------------------------
// K5: zq gather: out_zq[b][c][hw] = codebook[idx[b][hw]][c]. grid 512 x 256.
__global__ void vq_zq(const int* __restrict__ idx,
                      const float* __restrict__ cb, float* __restrict__ out) {
    __shared__ int sidx[64];
    __shared__ float lcb[64][129];  // +1 pad: conflict-free column reads
    int t = threadIdx.x;
    int b = blockIdx.x >> 4;
    int hw0 = (blockIdx.x & 15) * 64;
    if (t < 64) sidx[t] = idx[b * HW_NUM + hw0 + t];
    __syncthreads();
    for (int i = t; i < 2048; i += 256) {  // stage 64 gathered codebook rows
        int row = i >> 5;
        int col = (i & 31) * 4;
        float4 v = *reinterpret_cast<const float4*>(cb + (size_t)sidx[row] * D_NUM + col);
        lcb[row][col + 0] = v.x;
        lcb[row][col + 1] = v.y;
        lcb[row][col + 2] = v.z;
        lcb[row][col + 3] = v.w;
    }
    __syncthreads();
    int hwl = t & 63;
    int c0 = t >> 6;
#pragma unroll
    for (int cc = 0; cc < 32; ++cc) {
        int c = cc * 4 + c0;
        out[O_ZQ + (((size_t)b * D_NUM + c) << 10) + hw0 + hwl] = lcb[hwl][c];
    }
}

// ---------------------------------------------------------------------------
// K6: scalars + perplexity. grid 1 x 256.
__global__ void vq_finalize(float* __restrict__ out, const float* __restrict__ scal) {
    __shared__ float red[256];
    int t = threadIdx.x;
    float ent = 0.f;
    for (int k = t; k < K_NUM; k += 256) {
        float c = 0.f;
#pragma unroll
        for (int b = 0; b < B_NUM; ++b) c += out[O_IHIST + (size_t)b * K_NUM + k];
        float p = c * (1.f / 32768.f);
        ent += p * __logf(p + 1e-10f);
    }
    red[t] = ent;
    __syncthreads();
    for (int s = 128; s; s >>= 1) {
        if (t < s) red[t] += red[t + s];
        __syncthreads();
    }
    if (t == 0) {
        float mse = scal[0] * (1.f / (32768.f * 128.f));  // fwd: quant == commit
        out[O_LOSS] = 1.25f * mse;                        // q + 0.25*c + 0*sm
        out[O_PERP] = __expf(-red[0]);
        out[O_COMMIT] = mse;
        out[O_QUANT] = mse;
        out[O_SM] = scal[1] * (1.f / 32768.f);            // mean log(sum exp(m-d))
    }
}

// ---------------------------------------------------------------------------
extern "C" void kernel_launch(void* const* d_in, const int* in_sizes, int n_in,
                              void* d_out, int out_size, void* d_ws, size_t ws_size,
                              hipStream_t stream) {
    const float* z = (const float*)d_in[0];
    const float* cb = (const float*)d_in[1];
    float* out = (float*)d_out;
    char* ws = (char*)d_ws;

    int* idx_ws = (int*)(ws + WS_IDX);
    float* scal = (float*)(ws + WS_SCAL);
    float* eTi = (float*)(ws + WS_ET);
    float* cnorm = (float*)(ws + WS_CNORM);
    float* wsh = (float*)(ws + WS_HIST);
    const bool big = ws_size >= WS_END;

    // zero accumulators + the onehot plane (ws/d_out are poisoned pre-launch)
    hipMemsetAsync(scal, 0, 2 * sizeof(float), stream);
    hipMemsetAsync(out + O_IHIST, 0, 2 * B_NUM * K_NUM * sizeof(float), stream);
    hipMemsetAsync(out + O_ONEHOT, 0, (size_t)B_NUM * K_NUM * HW_NUM * sizeof(float),
                   stream);

    vq_prep<<<32, 256, 0, stream>>>(cb, eTi, cnorm);
    if (big)
        vq_main<true><<<2048, 512, 0, stream>>>(z, eTi, cnorm, out, idx_ws, scal, wsh);
    else
        vq_main<false><<<2048, 512, 0, stream>>>(z, eTi, cnorm, out, idx_ws, scal, wsh);
    vq_scatter<<<128, 256, 0, stream>>>(idx_ws, out);
    vq_zq<<<512, 256, 0, stream>>>(idx_ws, cb, out);
    if (big) vq_hist<<<256, 256, 0, stream>>>(wsh, out);
    vq_finalize<<<1, 256, 0, stream>>>(out, scal);
}

// Round 11
// 595.002 us; speedup vs baseline: 1.5483x; 1.5483x over previous
//
#include <hip/hip_runtime.h>
#include <hip/hip_bf16.h>
#include <float.h>

// VectorQuantizer forward, MI355X.
// z: [32,128,32,32] fp32, codebook: [2048,128] fp32.
// Outputs (flat fp32, concatenated):
//   loss(1), zq_ste(4194304), perplexity(1), onehot_img(67108864),
//   idx_img(32768), index_hist(65536), softmax_hist(65536),
//   commitment(1), quantization(1), softmax_loss(1)  => 71467013 total.
//
// R11 = R9 resubmitted unchanged (5th broker timeout; never measured).
// R9: R7's MFMA kernel + EXACT-ARGMIN REFINEMENT. R8 failed ONLY on idx_img
// (absmax 1215 <= few near-tie argmin flips from ~2e-4 split-bf16 noise; a
// layout bug would give ~2047). Fix: 4th MFMA (zl*el, free) + recompute
// candidates within EPS=0.01 of the approx min in exact fp32 (R6's FMA
// ordering, which matched np argmin with zero flips), merge exact argmin.
// Approx-dist error budget with 4 terms: ~3e-5 << EPS (160x margin).

#define K_NUM 2048
#define D_NUM 128
#define B_NUM 32
#define HW_NUM 1024
#define N_NUM 32768
#define REF_EPS 0.01f

typedef __attribute__((ext_vector_type(8))) short bf16x8;
typedef __attribute__((ext_vector_type(4))) float f32x4;

// out offsets (in floats)
#define O_LOSS   0ull
#define O_ZQ     1ull
#define O_PERP   4194305ull
#define O_ONEHOT 4194306ull
#define O_IDX    71303170ull
#define O_IHIST  71335938ull
#define O_SHIST  71401474ull
#define O_COMMIT 71467010ull
#define O_QUANT  71467011ull
#define O_SM     71467012ull

// ws offsets (bytes)
#define WS_IDX    0ull        // 32768 * 4 (int idx per position)
#define WS_SCAL   131072ull   // 2 floats: sum(min_dist), sum(log l)
#define WS_EB     131328ull   // 1 MiB: [dc:4][ct:128][hl:2][lane:64][16B] bf16 frags
#define WS_CNORM  1179904ull  // 2048 * 4  (||e_k||^2)
#define WS_HIST   1188096ull  // 2048*2048*4 = 16 MiB per-block softmax-hist partials
#define WS_END    17965312ull

// ---------------------------------------------------------------------------
// Exact fp32 distance for refinement. Replicates R6's (passing) rounding:
// serial ascending FMA chain with w = -2*e (exact scale), d = dot + (zn+cn).
__device__ __noinline__ float vq_exact_dist(const float* zrow, const float* erow,
                                            float zncn) {
    float dot = 0.f;
    for (int c = 0; c < 128; c += 4) {
        float4 zz = *reinterpret_cast<const float4*>(zrow + c);
        float4 ee = *reinterpret_cast<const float4*>(erow + c);
        dot = fmaf(zz.x, -2.f * ee.x, dot);
        dot = fmaf(zz.y, -2.f * ee.y, dot);
        dot = fmaf(zz.z, -2.f * ee.z, dot);
        dot = fmaf(zz.w, -2.f * ee.w, dot);
    }
    return dot + zncn;
}

// ---------------------------------------------------------------------------
// K1: pack e' = -2*codebook into MFMA B-fragment order, hi/lo bf16 (truncated
// split); cnorm[k] = ||e_k||^2. Lane l -> col=l&15, k-chunk (l>>4)*8+j; even j
// in low u16. grid 32 x 256: thread = (k = blk*64 + tid>>2, dc = tid&3).
__global__ void vq_prep(const float* __restrict__ cb, uint* __restrict__ ebuf,
                        float* __restrict__ cnorm) {
    int k = blockIdx.x * 64 + (threadIdx.x >> 2);
    int dc = threadIdx.x & 3;
    float v[32];
    float s = 0.f;
#pragma unroll
    for (int i = 0; i < 8; ++i) {
        float4 x = *reinterpret_cast<const float4*>(cb + (size_t)k * D_NUM + dc * 32 + i * 4);
        v[i * 4 + 0] = x.x; v[i * 4 + 1] = x.y; v[i * 4 + 2] = x.z; v[i * 4 + 3] = x.w;
        s += x.x * x.x + x.y * x.y + x.z * x.z + x.w * x.w;
    }
    s += __shfl_xor(s, 1, 64);
    s += __shfl_xor(s, 2, 64);
    if (dc == 0) cnorm[k] = s;

    int ct = k >> 4, col = k & 15;
    uint4* eb4 = reinterpret_cast<uint4*>(ebuf);
#pragma unroll
    for (int g = 0; g < 4; ++g) {
        uint hw_[4], lw_[4];
#pragma unroll
        for (int t = 0; t < 4; ++t) {
            float x0 = -2.f * v[g * 8 + 2 * t];
            float x1 = -2.f * v[g * 8 + 2 * t + 1];
            uint u0 = __builtin_bit_cast(uint, x0);
            uint u1 = __builtin_bit_cast(uint, x1);
            uint h0 = u0 & 0xffff0000u, h1 = u1 & 0xffff0000u;
            float l0 = x0 - __builtin_bit_cast(float, h0);
            float l1 = x1 - __builtin_bit_cast(float, h1);
            hw_[t] = (h0 >> 16) | h1;
            lw_[t] = (__builtin_bit_cast(uint, l0) >> 16)
                   | (__builtin_bit_cast(uint, l1) & 0xffff0000u);
        }
        int lanedst = (g << 4) | col;
        size_t base = ((size_t)(dc * 128 + ct) * 2) * 64 + lanedst;
        uint4 uh; uh.x = hw_[0]; uh.y = hw_[1]; uh.z = hw_[2]; uh.w = hw_[3];
        uint4 ul; ul.x = lw_[0]; ul.y = lw_[1]; ul.z = lw_[2]; ul.w = lw_[3];
        eb4[base] = uh;
        eb4[base + 64] = ul;
    }
}

// ---------------------------------------------------------------------------
// K2: MFMA distances + exact-refined argmin + softmax stats + hists.
// grid 2048 x 512. Block = 16 pos x 2048 codes; wave w owns 256 codes.
// Lane holds pos = (lane>>4)*4 + reg, code = w*256 + ft*16 + (lane&15).
template <bool WSH>
__global__ __launch_bounds__(512, 2) void vq_main(
    const float* __restrict__ z, const float* __restrict__ cb,
    const uint* __restrict__ ebuf, const float* __restrict__ cnorm,
    float* __restrict__ out, int* __restrict__ idx_ws, float* __restrict__ scal,
    float* __restrict__ wsh) {
    __shared__ __align__(16) float zt[16][132];  // +4 pad: 528B rows
    __shared__ float mredA[8][16];               // approx-min merge
    __shared__ float mredE[8][16];               // exact-candidate merge
    __shared__ int iredE[8][16];
    __shared__ float lred[8][16];

    const int tid = threadIdx.x;
    const int lane = tid & 63;
    const int wv = tid >> 6;
    const int col = lane & 15;
    const int g = lane >> 4;
    const int b = blockIdx.x >> 6;
    const int hw0 = (blockIdx.x & 63) * 16;
    const int n0 = blockIdx.x * 16;

    // stage z tile: z[b][d][hw0+pos] -> zt[pos][d]; one float4 per thread
    {
        const float* zb = z + (size_t)b * (D_NUM * HW_NUM) + hw0;
        int d = tid >> 2, q = tid & 3;
        float4 v = *reinterpret_cast<const float4*>(zb + d * HW_NUM + q * 4);
        zt[q * 4 + 0][d] = v.x;
        zt[q * 4 + 1][d] = v.y;
        zt[q * 4 + 2][d] = v.z;
        zt[q * 4 + 3][d] = v.w;
    }
    __syncthreads();

    // A-fragments (hi/lo truncated split), register-resident
    bf16x8 ah[4], al[4];
#pragma unroll
    for (int dc = 0; dc < 4; ++dc) {
        const float* zr = &zt[col][dc * 32 + g * 8];
        float x[8];
        *reinterpret_cast<float4*>(&x[0]) = *reinterpret_cast<const float4*>(zr);
        *reinterpret_cast<float4*>(&x[4]) = *reinterpret_cast<const float4*>(zr + 4);
        uint hw_[4], lw_[4];
#pragma unroll
        for (int t = 0; t < 4; ++t) {
            uint u0 = __builtin_bit_cast(uint, x[2 * t]);
            uint u1 = __builtin_bit_cast(uint, x[2 * t + 1]);
            uint h0 = u0 & 0xffff0000u, h1 = u1 & 0xffff0000u;
            float l0 = x[2 * t] - __builtin_bit_cast(float, h0);
            float l1 = x[2 * t + 1] - __builtin_bit_cast(float, h1);
            hw_[t] = (h0 >> 16) | h1;
            lw_[t] = (__builtin_bit_cast(uint, l0) >> 16)
                   | (__builtin_bit_cast(uint, l1) & 0xffff0000u);
        }
        uint4 uh; uh.x = hw_[0]; uh.y = hw_[1]; uh.z = hw_[2]; uh.w = hw_[3];
        uint4 ul; ul.x = lw_[0]; ul.y = lw_[1]; ul.z = lw_[2]; ul.w = lw_[3];
        ah[dc] = __builtin_bit_cast(bf16x8, uh);
        al[dc] = __builtin_bit_cast(bf16x8, ul);
    }

    f32x4 acc[16];
#pragma unroll
    for (int ft = 0; ft < 16; ++ft) acc[ft] = (f32x4){0.f, 0.f, 0.f, 0.f};

    // K-loop: 4 dc x 16 ft x (2 loads + 4 MFMA). No barriers; B from L2.
    const uint4* eb4 = reinterpret_cast<const uint4*>(ebuf);
    const int ctbase = wv << 4;
#pragma unroll
    for (int dc = 0; dc < 4; ++dc) {
#pragma unroll
        for (int ft = 0; ft < 16; ++ft) {
            size_t base = ((size_t)(dc * 128 + ctbase + ft) * 2) * 64 + lane;
            uint4 uh = eb4[base];
            uint4 ul = eb4[base + 64];
            bf16x8 bh = __builtin_bit_cast(bf16x8, uh);
            bf16x8 bl = __builtin_bit_cast(bf16x8, ul);
            acc[ft] = __builtin_amdgcn_mfma_f32_16x16x32_bf16(ah[dc], bh, acc[ft], 0, 0, 0);
            acc[ft] = __builtin_amdgcn_mfma_f32_16x16x32_bf16(al[dc], bh, acc[ft], 0, 0, 0);
            acc[ft] = __builtin_amdgcn_mfma_f32_16x16x32_bf16(ah[dc], bl, acc[ft], 0, 0, 0);
            acc[ft] = __builtin_amdgcn_mfma_f32_16x16x32_bf16(al[dc], bl, acc[ft], 0, 0, 0);
        }
    }

    // znorm (exact fp32): pos = lane>>2, quarter = lane&3
    float zn[4];
    {
        int pz = lane >> 2, part = lane & 3;
        const float* zr = &zt[pz][part * 32];
        float s = 0.f;
#pragma unroll
        for (int i = 0; i < 8; ++i) {
            float4 x = *reinterpret_cast<const float4*>(zr + i * 4);
            s += x.x * x.x + x.y * x.y + x.z * x.z + x.w * x.w;
        }
        s += __shfl_xor(s, 1, 64);
        s += __shfl_xor(s, 2, 64);
#pragma unroll
        for (int r = 0; r < 4; ++r) zn[r] = __shfl(s, (g * 4 + r) * 4, 64);
    }
    float cnv[16];
#pragma unroll
    for (int ft = 0; ft < 16; ++ft) cnv[ft] = cnorm[(wv << 8) + (ft << 4) + col];

    // approx dist = zn + cn + dot' (in place in acc)
#pragma unroll
    for (int ft = 0; ft < 16; ++ft)
#pragma unroll
        for (int r = 0; r < 4; ++r) acc[ft][r] += zn[r] + cnv[ft];

    // approx min per position (value only): 16-lane butterfly + 8-wave merge
    float mhat[4];
#pragma unroll
    for (int r = 0; r < 4; ++r) {
        float mv = acc[0][r];
#pragma unroll
        for (int ft = 1; ft < 16; ++ft) mv = fminf(mv, acc[ft][r]);
#pragma unroll
        for (int off = 1; off < 16; off <<= 1) mv = fminf(mv, __shfl_xor(mv, off, 64));
        if (col == 0) mredA[wv][g * 4 + r] = mv;
        mhat[r] = mv;
    }
    __syncthreads();
#pragma unroll
    for (int r = 0; r < 4; ++r) {
        int pos = g * 4 + r;
#pragma unroll
        for (int w = 0; w < 8; ++w) mhat[r] = fminf(mhat[r], mredA[w][pos]);
    }

    // exact refinement: recompute candidates within REF_EPS of approx min
    float cm[4] = {FLT_MAX, FLT_MAX, FLT_MAX, FLT_MAX};
    int ci[4] = {0x7fffffff, 0x7fffffff, 0x7fffffff, 0x7fffffff};
#pragma unroll
    for (int ft = 0; ft < 16; ++ft) {
#pragma unroll
        for (int r = 0; r < 4; ++r) {
            if (acc[ft][r] <= mhat[r] + REF_EPS) {
                int kk = (wv << 8) + (ft << 4) + col;
                float d = vq_exact_dist(&zt[g * 4 + r][0], cb + (size_t)kk * D_NUM,
                                        zn[r] + cnv[ft]);
                if (d < cm[r] || (d == cm[r] && kk < ci[r])) { cm[r] = d; ci[r] = kk; }
            }
        }
    }
    float mstar[4];
    int kstar[4];
#pragma unroll
    for (int r = 0; r < 4; ++r) {
        float mv = cm[r];
        int mi = ci[r];
#pragma unroll
        for (int off = 1; off < 16; off <<= 1) {
            float ov = __shfl_xor(mv, off, 64);
            int oi = __shfl_xor(mi, off, 64);
            if (ov < mv || (ov == mv && oi < mi)) { mv = ov; mi = oi; }
        }
        if (col == 0) { mredE[wv][g * 4 + r] = mv; iredE[wv][g * 4 + r] = mi; }
        mstar[r] = mv;
        kstar[r] = mi;
    }
    __syncthreads();
#pragma unroll
    for (int r = 0; r < 4; ++r) {
        int pos = g * 4 + r;
#pragma unroll
        for (int w = 0; w < 8; ++w) {
            float ov = mredE[w][pos];
            int oi = iredE[w][pos];
            if (ov < mstar[r] || (ov == mstar[r] && oi < kstar[r])) {
                mstar[r] = ov;
                kstar[r] = oi;
            }
        }
    }

    // P = exp(mhat - d) in place; per-wave l partial, then 8-way merge
#pragma unroll
    for (int r = 0; r < 4; ++r) {
        float s = 0.f;
#pragma unroll
        for (int ft = 0; ft < 16; ++ft) {
            float t = __expf(mhat[r] - acc[ft][r]);
            acc[ft][r] = t;
            s += t;
        }
#pragma unroll
        for (int off = 1; off < 16; off <<= 1) s += __shfl_xor(s, off, 64);
        if (col == 0) lred[wv][g * 4 + r] = s;
    }
    __syncthreads();
    float lf[4], rinv[4];
#pragma unroll
    for (int r = 0; r < 4; ++r) {
        float s = 0.f;
        int pos = g * 4 + r;
#pragma unroll
        for (int w = 0; w < 8; ++w) s += lred[w][pos];
        lf[r] = s;
        rinv[r] = 1.f / s;
    }

    // softmax hist: h(code) summed over the block's 16 pos (xor over g-bits)
#pragma unroll
    for (int ft = 0; ft < 16; ++ft) {
        float h = 0.f;
#pragma unroll
        for (int r = 0; r < 4; ++r) h += acc[ft][r] * rinv[r];
        h += __shfl_xor(h, 16, 64);
        h += __shfl_xor(h, 32, 64);
        if (WSH) {
            if (lane < 16)
                wsh[(size_t)blockIdx.x * K_NUM + (wv << 8) + (ft << 4) + lane] = h;
        } else {
            if (lane < 16)
                atomicAdd(&out[O_SHIST + (size_t)b * K_NUM + (wv << 8) + (ft << 4) + lane], h);
        }
    }

    // idx / index_hist / scalar sums (wave 0; col==0 lanes own 4 pos each)
    if (wv == 0) {
        float summ = 0.f, suml = 0.f;
        if (col == 0) {
#pragma unroll
            for (int r = 0; r < 4; ++r) {
                int n = n0 + g * 4 + r;
                idx_ws[n] = kstar[r];
                out[O_IDX + n] = (float)kstar[r];
                atomicAdd(&out[O_IHIST + (size_t)b * K_NUM + kstar[r]], 1.0f);
                summ += mstar[r];
                suml += __logf(lf[r]);
            }
        }
        summ += __shfl_xor(summ, 16, 64);
        summ += __shfl_xor(summ, 32, 64);
        suml += __shfl_xor(suml, 16, 64);
        suml += __shfl_xor(suml, 32, 64);
        if (lane == 0) {
            atomicAdd(&scal[0], summ);
            atomicAdd(&scal[1], suml);
        }
    }
}

// ---------------------------------------------------------------------------
// K3: softmax_hist reduce: out[b][k] = sum over 64 sub-blocks. grid 256 x 256.
__global__ void vq_hist(const float* __restrict__ wsh, float* __restrict__ out) {
    int gid = blockIdx.x * 256 + threadIdx.x;  // 0..65535 = b*2048 + k
    int b = gid >> 11;
    int k = gid & 2047;
    const float* p = wsh + ((size_t)b * 64) * K_NUM + k;
    float s = 0.f;
#pragma unroll
    for (int sb = 0; sb < 64; ++sb) s += p[(size_t)sb * K_NUM];
    out[O_SHIST + gid] = s;
}

// ---------------------------------------------------------------------------
// K4: scatter ones into memset-zeroed onehot_img. grid 128 x 256.
__global__ void vq_scatter(const int* __restrict__ idx, float* __restrict__ out) {
    int n = blockIdx.x * 256 + threadIdx.x;  // 0..32767
    int b = n >> 10;
    int hw = n & 1023;
    int k = idx[n];
    out[O_ONEHOT + (((size_t)b * K_NUM + k) << 10) + hw] = 1.0f;
}

// ---------------------------------------------------------------------------
// K5: zq gather: out_zq[b][c][hw] = codebook[idx[b][hw]][c]. grid 512 x 256.
__global__ void vq_zq(const int* __restrict__ idx,
                      const float* __restrict__ cb, float* __restrict__ out) {
    __shared__ int sidx[64];
    __shared__ float lcb[64][129];  // +1 pad: conflict-free column reads
    int t = threadIdx.x;
    int b = blockIdx.x >> 4;
    int hw0 = (blockIdx.x & 15) * 64;
    if (t < 64) sidx[t] = idx[b * HW_NUM + hw0 + t];
    __syncthreads();
    for (int i = t; i < 2048; i += 256) {  // stage 64 gathered codebook rows
        int row = i >> 5;
        int col = (i & 31) * 4;
        float4 v = *reinterpret_cast<const float4*>(cb + (size_t)sidx[row] * D_NUM + col);
        lcb[row][col + 0] = v.x;
        lcb[row][col + 1] = v.y;
        lcb[row][col + 2] = v.z;
        lcb[row][col + 3] = v.w;
    }
    __syncthreads();
    int hwl = t & 63;
    int c0 = t >> 6;
#pragma unroll
    for (int cc = 0; cc < 32; ++cc) {
        int c = cc * 4 + c0;
        out[O_ZQ + (((size_t)b * D_NUM + c) << 10) + hw0 + hwl] = lcb[hwl][c];
    }
}

// ---------------------------------------------------------------------------
// K6: scalars + perplexity. grid 1 x 256.
__global__ void vq_finalize(float* __restrict__ out, const float* __restrict__ scal) {
    __shared__ float red[256];
    int t = threadIdx.x;
    float ent = 0.f;
    for (int k = t; k < K_NUM; k += 256) {
        float c = 0.f;
#pragma unroll
        for (int b = 0; b < B_NUM; ++b) c += out[O_IHIST + (size_t)b * K_NUM + k];
        float p = c * (1.f / 32768.f);
        ent += p * __logf(p + 1e-10f);
    }
    red[t] = ent;
    __syncthreads();
    for (int s = 128; s; s >>= 1) {
        if (t < s) red[t] += red[t + s];
        __syncthreads();
    }
    if (t == 0) {
        float mse = scal[0] * (1.f / (32768.f * 128.f));  // fwd: quant == commit
        out[O_LOSS] = 1.25f * mse;                        // q + 0.25*c + 0*sm
        out[O_PERP] = __expf(-red[0]);
        out[O_COMMIT] = mse;
        out[O_QUANT] = mse;
        out[O_SM] = scal[1] * (1.f / 32768.f);            // mean log(sum exp(m-d))
    }
}

// ---------------------------------------------------------------------------
extern "C" void kernel_launch(void* const* d_in, const int* in_sizes, int n_in,
                              void* d_out, int out_size, void* d_ws, size_t ws_size,
                              hipStream_t stream) {
    const float* z = (const float*)d_in[0];
    const float* cb = (const float*)d_in[1];
    float* out = (float*)d_out;
    char* ws = (char*)d_ws;

    int* idx_ws = (int*)(ws + WS_IDX);
    float* scal = (float*)(ws + WS_SCAL);
    uint* ebuf = (uint*)(ws + WS_EB);
    float* cnorm = (float*)(ws + WS_CNORM);
    float* wsh = (float*)(ws + WS_HIST);
    const bool big = ws_size >= WS_END;

    // zero accumulators + the onehot plane (ws/d_out are poisoned pre-launch)
    hipMemsetAsync(scal, 0, 2 * sizeof(float), stream);
    hipMemsetAsync(out + O_IHIST, 0, 2 * B_NUM * K_NUM * sizeof(float), stream);
    hipMemsetAsync(out + O_ONEHOT, 0, (size_t)B_NUM * K_NUM * HW_NUM * sizeof(float),
                   stream);

    vq_prep<<<32, 256, 0, stream>>>(cb, ebuf, cnorm);
    if (big)
        vq_main<true><<<2048, 512, 0, stream>>>(z, cb, ebuf, cnorm, out, idx_ws, scal, wsh);
    else
        vq_main<false><<<2048, 512, 0, stream>>>(z, cb, ebuf, cnorm, out, idx_ws, scal, wsh);
    vq_scatter<<<128, 256, 0, stream>>>(idx_ws, out);
    vq_zq<<<512, 256, 0, stream>>>(idx_ws, cb, out);
    if (big) vq_hist<<<256, 256, 0, stream>>>(wsh, out);
    vq_finalize<<<1, 256, 0, stream>>>(out, scal);
}

// Round 12
// 590.052 us; speedup vs baseline: 1.5613x; 1.0084x over previous
//
#include <hip/hip_runtime.h>
#include <hip/hip_bf16.h>
#include <float.h>

// VectorQuantizer forward, MI355X.
// z: [32,128,32,32] fp32, codebook: [2048,128] fp32.
// Outputs (flat fp32, concatenated):
//   loss(1), zq_ste(4194304), perplexity(1), onehot_img(67108864),
//   idx_img(32768), index_hist(65536), softmax_hist(65536),
//   commitment(1), quantization(1), softmax_loss(1)  => 71467013 total.
//
// R12: R11 passed (595us; vq_main 259us). Counters: MfmaUtil 10.9% == exact
// MFMA work (28us), VALU 23%, rest = L2 load latency (VGPR=112 -> ~2 load
// pairs in flight; 2GiB L2 reads at 8.1 of 34.5 TB/s). Fixes:
// (1) explicit 4-slot software pipeline of B-frag loads (~8 in flight/wave),
//     A-frags regenerated per-dc from LDS + drop zl*bl MFMA to stay <=128
//     VGPR (16-waves/CU cliff at 128, m69). Approx err ~2e-4 (R8-measured);
//     exact-argmin refinement keeps idx_img exact.
// (2) fused one-pass onehot (compare+float2 stores) replacing 268MB memset +
//     scatter (tail had 336us unaccounted; memset fill BW unprofiled).

#define K_NUM 2048
#define D_NUM 128
#define B_NUM 32
#define HW_NUM 1024
#define N_NUM 32768
#define REF_EPS 0.01f

typedef __attribute__((ext_vector_type(8))) short bf16x8;
typedef __attribute__((ext_vector_type(4))) float f32x4;

// out offsets (in floats)
#define O_LOSS   0ull
#define O_ZQ     1ull
#define O_PERP   4194305ull
#define O_ONEHOT 4194306ull
#define O_IDX    71303170ull
#define O_IHIST  71335938ull
#define O_SHIST  71401474ull
#define O_COMMIT 71467010ull
#define O_QUANT  71467011ull
#define O_SM     71467012ull

// ws offsets (bytes)
#define WS_IDX    0ull        // 32768 * 4 (int idx per position)
#define WS_SCAL   131072ull   // 2 floats: sum(min_dist), sum(log l)
#define WS_EB     131328ull   // 1 MiB: [dc:4][ct:128][hl:2][lane:64][16B] bf16 frags
#define WS_CNORM  1179904ull  // 2048 * 4  (||e_k||^2)
#define WS_HIST   1188096ull  // 2048*2048*4 = 16 MiB per-block softmax-hist partials
#define WS_END    17965312ull

// ---------------------------------------------------------------------------
// Exact fp32 distance for refinement. Replicates R6's (passing) rounding:
// serial ascending FMA chain with w = -2*e (exact scale), d = dot + (zn+cn).
__device__ __noinline__ float vq_exact_dist(const float* zrow, const float* erow,
                                            float zncn) {
    float dot = 0.f;
    for (int c = 0; c < 128; c += 4) {
        float4 zz = *reinterpret_cast<const float4*>(zrow + c);
        float4 ee = *reinterpret_cast<const float4*>(erow + c);
        dot = fmaf(zz.x, -2.f * ee.x, dot);
        dot = fmaf(zz.y, -2.f * ee.y, dot);
        dot = fmaf(zz.z, -2.f * ee.z, dot);
        dot = fmaf(zz.w, -2.f * ee.w, dot);
    }
    return dot + zncn;
}

// ---------------------------------------------------------------------------
// K1: pack e' = -2*codebook into MFMA B-fragment order, hi/lo bf16 (truncated
// split); cnorm[k] = ||e_k||^2. Lane l -> col=l&15, k-chunk (l>>4)*8+j; even j
// in low u16. grid 32 x 256: thread = (k = blk*64 + tid>>2, dc = tid&3).
__global__ void vq_prep(const float* __restrict__ cb, uint* __restrict__ ebuf,
                        float* __restrict__ cnorm) {
    int k = blockIdx.x * 64 + (threadIdx.x >> 2);
    int dc = threadIdx.x & 3;
    float v[32];
    float s = 0.f;
#pragma unroll
    for (int i = 0; i < 8; ++i) {
        float4 x = *reinterpret_cast<const float4*>(cb + (size_t)k * D_NUM + dc * 32 + i * 4);
        v[i * 4 + 0] = x.x; v[i * 4 + 1] = x.y; v[i * 4 + 2] = x.z; v[i * 4 + 3] = x.w;
        s += x.x * x.x + x.y * x.y + x.z * x.z + x.w * x.w;
    }
    s += __shfl_xor(s, 1, 64);
    s += __shfl_xor(s, 2, 64);
    if (dc == 0) cnorm[k] = s;

    int ct = k >> 4, col = k & 15;
    uint4* eb4 = reinterpret_cast<uint4*>(ebuf);
#pragma unroll
    for (int g = 0; g < 4; ++g) {
        uint hw_[4], lw_[4];
#pragma unroll
        for (int t = 0; t < 4; ++t) {
            float x0 = -2.f * v[g * 8 + 2 * t];
            float x1 = -2.f * v[g * 8 + 2 * t + 1];
            uint u0 = __builtin_bit_cast(uint, x0);
            uint u1 = __builtin_bit_cast(uint, x1);
            uint h0 = u0 & 0xffff0000u, h1 = u1 & 0xffff0000u;
            float l0 = x0 - __builtin_bit_cast(float, h0);
            float l1 = x1 - __builtin_bit_cast(float, h1);
            hw_[t] = (h0 >> 16) | h1;
            lw_[t] = (__builtin_bit_cast(uint, l0) >> 16)
                   | (__builtin_bit_cast(uint, l1) & 0xffff0000u);
        }
        int lanedst = (g << 4) | col;
        size_t base = ((size_t)(dc * 128 + ct) * 2) * 64 + lanedst;
        uint4 uh; uh.x = hw_[0]; uh.y = hw_[1]; uh.z = hw_[2]; uh.w = hw_[3];
        uint4 ul; ul.x = lw_[0]; ul.y = lw_[1]; ul.z = lw_[2]; ul.w = lw_[3];
        eb4[base] = uh;
        eb4[base + 64] = ul;
    }
}

// ---------------------------------------------------------------------------
// K2: MFMA distances + exact-refined argmin + softmax stats + hists.
// grid 2048 x 512. Block = 16 pos x 2048 codes; wave w owns 256 codes.
// Lane holds pos = (lane>>4)*4 + reg, code = w*256 + ft*16 + (lane&15).
// K-loop: 4-slot software-pipelined B loads, 3 MFMAs per pair (zh*eh +
// zl*eh + zh*el), A-frags regenerated per dc (VGPR <= 128 target).
template <bool WSH>
__global__ __launch_bounds__(512, 2) void vq_main(
    const float* __restrict__ z, const float* __restrict__ cb,
    const uint* __restrict__ ebuf, const float* __restrict__ cnorm,
    float* __restrict__ out, int* __restrict__ idx_ws, float* __restrict__ scal,
    float* __restrict__ wsh) {
    __shared__ __align__(16) float zt[16][132];  // +4 pad: 528B rows
    __shared__ float mredA[8][16];               // approx-min merge
    __shared__ float mredE[8][16];               // exact-candidate merge
    __shared__ int iredE[8][16];
    __shared__ float lred[8][16];

    const int tid = threadIdx.x;
    const int lane = tid & 63;
    const int wv = tid >> 6;
    const int col = lane & 15;
    const int g = lane >> 4;
    const int b = blockIdx.x >> 6;
    const int hw0 = (blockIdx.x & 63) * 16;
    const int n0 = blockIdx.x * 16;

    // stage z tile: z[b][d][hw0+pos] -> zt[pos][d]; one float4 per thread
    {
        const float* zb = z + (size_t)b * (D_NUM * HW_NUM) + hw0;
        int d = tid >> 2, q = tid & 3;
        float4 v = *reinterpret_cast<const float4*>(zb + d * HW_NUM + q * 4);
        zt[q * 4 + 0][d] = v.x;
        zt[q * 4 + 1][d] = v.y;
        zt[q * 4 + 2][d] = v.z;
        zt[q * 4 + 3][d] = v.w;
    }
    __syncthreads();

    f32x4 acc[16];
#pragma unroll
    for (int ft = 0; ft < 16; ++ft) acc[ft] = (f32x4){0.f, 0.f, 0.f, 0.f};

    const uint4* eb4 = reinterpret_cast<const uint4*>(ebuf);
    const int ctbase = wv << 4;

    // pipeline slots (static-indexed after unroll; rule #20)
    uint4 su[4], sv[4];
#define LOADP(slot, DC, FT)                                                    \
    {                                                                          \
        size_t base_ = ((size_t)((DC) * 128 + ctbase + (FT)) * 2) * 64 + lane; \
        su[slot] = eb4[base_];                                                 \
        sv[slot] = eb4[base_ + 64];                                            \
    }

    // prologue: fill 4 slots (dc=0, ft=0..3)
    LOADP(0, 0, 0) LOADP(1, 0, 1) LOADP(2, 0, 2) LOADP(3, 0, 3)

#pragma unroll
    for (int dc = 0; dc < 4; ++dc) {
        // regenerate A-frags (hi/lo truncated split) for this dc from LDS
        bf16x8 ahc, alc;
        {
            const float* zr = &zt[col][dc * 32 + g * 8];
            float x[8];
            *reinterpret_cast<float4*>(&x[0]) = *reinterpret_cast<const float4*>(zr);
            *reinterpret_cast<float4*>(&x[4]) = *reinterpret_cast<const float4*>(zr + 4);
            uint hw_[4], lw_[4];
#pragma unroll
            for (int t = 0; t < 4; ++t) {
                uint u0 = __builtin_bit_cast(uint, x[2 * t]);
                uint u1 = __builtin_bit_cast(uint, x[2 * t + 1]);
                uint h0 = u0 & 0xffff0000u, h1 = u1 & 0xffff0000u;
                float l0 = x[2 * t] - __builtin_bit_cast(float, h0);
                float l1 = x[2 * t + 1] - __builtin_bit_cast(float, h1);
                hw_[t] = (h0 >> 16) | h1;
                lw_[t] = (__builtin_bit_cast(uint, l0) >> 16)
                       | (__builtin_bit_cast(uint, l1) & 0xffff0000u);
            }
            uint4 uh; uh.x = hw_[0]; uh.y = hw_[1]; uh.z = hw_[2]; uh.w = hw_[3];
            uint4 ul; ul.x = lw_[0]; ul.y = lw_[1]; ul.z = lw_[2]; ul.w = lw_[3];
            ahc = __builtin_bit_cast(bf16x8, uh);
            alc = __builtin_bit_cast(bf16x8, ul);
        }
#pragma unroll
        for (int ft = 0; ft < 16; ++ft) {
            const int slot = ft & 3;
            bf16x8 bh = __builtin_bit_cast(bf16x8, su[slot]);
            bf16x8 bl = __builtin_bit_cast(bf16x8, sv[slot]);
            acc[ft] = __builtin_amdgcn_mfma_f32_16x16x32_bf16(ahc, bh, acc[ft], 0, 0, 0);
            acc[ft] = __builtin_amdgcn_mfma_f32_16x16x32_bf16(alc, bh, acc[ft], 0, 0, 0);
            acc[ft] = __builtin_amdgcn_mfma_f32_16x16x32_bf16(ahc, bl, acc[ft], 0, 0, 0);
            const int tn = dc * 16 + ft + 4;
            if (tn < 64) { LOADP(slot, (tn >> 4), (tn & 15)) }
        }
    }
#undef LOADP

    // znorm (exact fp32): pos = lane>>2, quarter = lane&3
    float zn[4];
    {
        int pz = lane >> 2, part = lane & 3;
        const float* zr = &zt[pz][part * 32];
        float s = 0.f;
#pragma unroll
        for (int i = 0; i < 8; ++i) {
            float4 x = *reinterpret_cast<const float4*>(zr + i * 4);
            s += x.x * x.x + x.y * x.y + x.z * x.z + x.w * x.w;
        }
        s += __shfl_xor(s, 1, 64);
        s += __shfl_xor(s, 2, 64);
#pragma unroll
        for (int r = 0; r < 4; ++r) zn[r] = __shfl(s, (g * 4 + r) * 4, 64);
    }
    float cnv[16];
#pragma unroll
    for (int ft = 0; ft < 16; ++ft) cnv[ft] = cnorm[(wv << 8) + (ft << 4) + col];

    // approx dist = zn + cn + dot' (in place in acc)
#pragma unroll
    for (int ft = 0; ft < 16; ++ft)
#pragma unroll
        for (int r = 0; r < 4; ++r) acc[ft][r] += zn[r] + cnv[ft];

    // approx min per position (value only): 16-lane butterfly + 8-wave merge
    float mhat[4];
#pragma unroll
    for (int r = 0; r < 4; ++r) {
        float mv = acc[0][r];
#pragma unroll
        for (int ft = 1; ft < 16; ++ft) mv = fminf(mv, acc[ft][r]);
#pragma unroll
        for (int off = 1; off < 16; off <<= 1) mv = fminf(mv, __shfl_xor(mv, off, 64));
        if (col == 0) mredA[wv][g * 4 + r] = mv;
        mhat[r] = mv;
    }
    __syncthreads();
#pragma unroll
    for (int r = 0; r < 4; ++r) {
        int pos = g * 4 + r;
#pragma unroll
        for (int w = 0; w < 8; ++w) mhat[r] = fminf(mhat[r], mredA[w][pos]);
    }

    // exact refinement: recompute candidates within REF_EPS of approx min
    float cm[4] = {FLT_MAX, FLT_MAX, FLT_MAX, FLT_MAX};
    int ci[4] = {0x7fffffff, 0x7fffffff, 0x7fffffff, 0x7fffffff};
#pragma unroll
    for (int ft = 0; ft < 16; ++ft) {
#pragma unroll
        for (int r = 0; r < 4; ++r) {
            if (acc[ft][r] <= mhat[r] + REF_EPS) {
                int kk = (wv << 8) + (ft << 4) + col;
                float d = vq_exact_dist(&zt[g * 4 + r][0], cb + (size_t)kk * D_NUM,
                                        zn[r] + cnv[ft]);
                if (d < cm[r] || (d == cm[r] && kk < ci[r])) { cm[r] = d; ci[r] = kk; }
            }
        }
    }
    float mstar[4];
    int kstar[4];
#pragma unroll
    for (int r = 0; r < 4; ++r) {
        float mv = cm[r];
        int mi = ci[r];
#pragma unroll
        for (int off = 1; off < 16; off <<= 1) {
            float ov = __shfl_xor(mv, off, 64);
            int oi = __shfl_xor(mi, off, 64);
            if (ov < mv || (ov == mv && oi < mi)) { mv = ov; mi = oi; }
        }
        if (col == 0) { mredE[wv][g * 4 + r] = mv; iredE[wv][g * 4 + r] = mi; }
        mstar[r] = mv;
        kstar[r] = mi;
    }
    __syncthreads();
#pragma unroll
    for (int r = 0; r < 4; ++r) {
        int pos = g * 4 + r;
#pragma unroll
        for (int w = 0; w < 8; ++w) {
            float ov = mredE[w][pos];
            int oi = iredE[w][pos];
            if (ov < mstar[r] || (ov == mstar[r] && oi < kstar[r])) {
                mstar[r] = ov;
                kstar[r] = oi;
            }
        }
    }

    // P = exp(mhat - d) in place; per-wave l partial, then 8-way merge
#pragma unroll
    for (int r = 0; r < 4; ++r) {
        float s = 0.f;
#pragma unroll
        for (int ft = 0; ft < 16; ++ft) {
            float t = __expf(mhat[r] - acc[ft][r]);
            acc[ft][r] = t;
            s += t;
        }
#pragma unroll
        for (int off = 1; off < 16; off <<= 1) s += __shfl_xor(s, off, 64);
        if (col == 0) lred[wv][g * 4 + r] = s;
    }
    __syncthreads();
    float lf[4], rinv[4];
#pragma unroll
    for (int r = 0; r < 4; ++r) {
        float s = 0.f;
        int pos = g * 4 + r;
#pragma unroll
        for (int w = 0; w < 8; ++w) s += lred[w][pos];
        lf[r] = s;
        rinv[r] = 1.f / s;
    }

    // softmax hist: h(code) summed over the block's 16 pos (xor over g-bits)
#pragma unroll
    for (int ft = 0; ft < 16; ++ft) {
        float h = 0.f;
#pragma unroll
        for (int r = 0; r < 4; ++r) h += acc[ft][r] * rinv[r];
        h += __shfl_xor(h, 16, 64);
        h += __shfl_xor(h, 32, 64);
        if (WSH) {
            if (lane < 16)
                wsh[(size_t)blockIdx.x * K_NUM + (wv << 8) + (ft << 4) + lane] = h;
        } else {
            if (lane < 16)
                atomicAdd(&out[O_SHIST + (size_t)b * K_NUM + (wv << 8) + (ft << 4) + lane], h);
        }
    }

    // idx / index_hist / scalar sums (wave 0; col==0 lanes own 4 pos each)
    if (wv == 0) {
        float summ = 0.f, suml = 0.f;
        if (col == 0) {
#pragma unroll
            for (int r = 0; r < 4; ++r) {
                int n = n0 + g * 4 + r;
                idx_ws[n] = kstar[r];
                out[O_IDX + n] = (float)kstar[r];
                atomicAdd(&out[O_IHIST + (size_t)b * K_NUM + kstar[r]], 1.0f);
                summ += mstar[r];
                suml += __logf(lf[r]);
            }
        }
        summ += __shfl_xor(summ, 16, 64);
        summ += __shfl_xor(summ, 32, 64);
        suml += __shfl_xor(suml, 16, 64);
        suml += __shfl_xor(suml, 32, 64);
        if (lane == 0) {
            atomicAdd(&scal[0], summ);
            atomicAdd(&scal[1], suml);
        }
    }
}

// ---------------------------------------------------------------------------
// K3: softmax_hist reduce: out[b][k] = sum over 64 sub-blocks. grid 256 x 256.
__global__ void vq_hist(const float* __restrict__ wsh, float* __restrict__ out) {
    int gid = blockIdx.x * 256 + threadIdx.x;  // 0..65535 = b*2048 + k
    int b = gid >> 11;
    int k = gid & 2047;
    const float* p = wsh + ((size_t)b * 64) * K_NUM + k;
    float s = 0.f;
#pragma unroll
    for (int sb = 0; sb < 64; ++sb) s += p[(size_t)sb * K_NUM];
    out[O_SHIST + gid] = s;
}

// ---------------------------------------------------------------------------
// K4: fused onehot fill (single write pass; no memset, no scatter).
// onehot[b][k][hw] = (idx[b*1024+hw] == k). 4 floats/thread via 2 float2
// stores (O_ONEHOT is 8B-aligned only). grid 65536 x 256.
__global__ void vq_onehot(const int* __restrict__ idx, float* __restrict__ out) {
    size_t gid = (size_t)blockIdx.x * 256 + threadIdx.x;
    size_t i = gid * 4;
    int hw = (int)(i & 1023);
    int k = (int)((i >> 10) & 2047);
    int b = (int)(i >> 21);
    int4 iv = *reinterpret_cast<const int4*>(idx + b * HW_NUM + hw);  // 16B-aligned
    float2 v0 = {iv.x == k ? 1.f : 0.f, iv.y == k ? 1.f : 0.f};
    float2 v1 = {iv.z == k ? 1.f : 0.f, iv.w == k ? 1.f : 0.f};
    *reinterpret_cast<float2*>(out + O_ONEHOT + i) = v0;
    *reinterpret_cast<float2*>(out + O_ONEHOT + i + 2) = v1;
}

// ---------------------------------------------------------------------------
// K5: zq gather: out_zq[b][c][hw] = codebook[idx[b][hw]][c]. grid 512 x 256.
__global__ void vq_zq(const int* __restrict__ idx,
                      const float* __restrict__ cb, float* __restrict__ out) {
    __shared__ int sidx[64];
    __shared__ float lcb[64][129];  // +1 pad: conflict-free column reads
    int t = threadIdx.x;
    int b = blockIdx.x >> 4;
    int hw0 = (blockIdx.x & 15) * 64;
    if (t < 64) sidx[t] = idx[b * HW_NUM + hw0 + t];
    __syncthreads();
    for (int i = t; i < 2048; i += 256) {  // stage 64 gathered codebook rows
        int row = i >> 5;
        int col = (i & 31) * 4;
        float4 v = *reinterpret_cast<const float4*>(cb + (size_t)sidx[row] * D_NUM + col);
        lcb[row][col + 0] = v.x;
        lcb[row][col + 1] = v.y;
        lcb[row][col + 2] = v.z;
        lcb[row][col + 3] = v.w;
    }
    __syncthreads();
    int hwl = t & 63;
    int c0 = t >> 6;
#pragma unroll
    for (int cc = 0; cc < 32; ++cc) {
        int c = cc * 4 + c0;
        out[O_ZQ + (((size_t)b * D_NUM + c) << 10) + hw0 + hwl] = lcb[hwl][c];
    }
}

// ---------------------------------------------------------------------------
// K6: scalars + perplexity. grid 1 x 256.
__global__ void vq_finalize(float* __restrict__ out, const float* __restrict__ scal) {
    __shared__ float red[256];
    int t = threadIdx.x;
    float ent = 0.f;
    for (int k = t; k < K_NUM; k += 256) {
        float c = 0.f;
#pragma unroll
        for (int b = 0; b < B_NUM; ++b) c += out[O_IHIST + (size_t)b * K_NUM + k];
        float p = c * (1.f / 32768.f);
        ent += p * __logf(p + 1e-10f);
    }
    red[t] = ent;
    __syncthreads();
    for (int s = 128; s; s >>= 1) {
        if (t < s) red[t] += red[t + s];
        __syncthreads();
    }
    if (t == 0) {
        float mse = scal[0] * (1.f / (32768.f * 128.f));  // fwd: quant == commit
        out[O_LOSS] = 1.25f * mse;                        // q + 0.25*c + 0*sm
        out[O_PERP] = __expf(-red[0]);
        out[O_COMMIT] = mse;
        out[O_QUANT] = mse;
        out[O_SM] = scal[1] * (1.f / 32768.f);            // mean log(sum exp(m-d))
    }
}

// ---------------------------------------------------------------------------
extern "C" void kernel_launch(void* const* d_in, const int* in_sizes, int n_in,
                              void* d_out, int out_size, void* d_ws, size_t ws_size,
                              hipStream_t stream) {
    const float* z = (const float*)d_in[0];
    const float* cb = (const float*)d_in[1];
    float* out = (float*)d_out;
    char* ws = (char*)d_ws;

    int* idx_ws = (int*)(ws + WS_IDX);
    float* scal = (float*)(ws + WS_SCAL);
    uint* ebuf = (uint*)(ws + WS_EB);
    float* cnorm = (float*)(ws + WS_CNORM);
    float* wsh = (float*)(ws + WS_HIST);
    const bool big = ws_size >= WS_END;

    // zero the atomic accumulators (ws/d_out are poisoned pre-launch)
    hipMemsetAsync(scal, 0, 2 * sizeof(float), stream);
    hipMemsetAsync(out + O_IHIST, 0, 2 * B_NUM * K_NUM * sizeof(float), stream);

    vq_prep<<<32, 256, 0, stream>>>(cb, ebuf, cnorm);
    if (big)
        vq_main<true><<<2048, 512, 0, stream>>>(z, cb, ebuf, cnorm, out, idx_ws, scal, wsh);
    else
        vq_main<false><<<2048, 512, 0, stream>>>(z, cb, ebuf, cnorm, out, idx_ws, scal, wsh);
    vq_onehot<<<65536, 256, 0, stream>>>(idx_ws, out);
    vq_zq<<<512, 256, 0, stream>>>(idx_ws, cb, out);
    if (big) vq_hist<<<256, 256, 0, stream>>>(wsh, out);
    vq_finalize<<<1, 256, 0, stream>>>(out, scal);
}